// Round 7
// baseline (760.458 us; speedup 1.0000x reference)
//
#include <hip/hip_runtime.h>

#define D 128
#define CSR_STRIDE 64     // in-deg ~ Poisson(16); P(>64) ~ 0, guarded anyway
#define LDSTRIDE 136      // 128 + 8 pad: 16B-aligned, 2-way banks (free)
#define NCH 32            // edge chunks for binned histogram / fill
#define NR  8             // node ranges (12500 nodes * 4B = 50 KB LDS)

typedef short bh8 __attribute__((ext_vector_type(8)));
typedef float f32x4 __attribute__((ext_vector_type(4)));

__device__ __forceinline__ unsigned short f2b(float f) {
    unsigned u = __float_as_uint(f);
    u += 0x7fffu + ((u >> 16) & 1u);          // RNE
    return (unsigned short)(u >> 16);
}
__device__ __forceinline__ float b2f(unsigned short h) {
    return __uint_as_float(((unsigned)h) << 16);
}

// ------------------------------------------------------------ MFMA GEMM
// C[M x 128] = A[M x 128] @ W[128 x 128] via 16x16x32 bf16 MFMA.
// 256 thr = 4 waves; tile 128x128; wave = 64x64 (4x4 mfma). WT is n-major.
// AMODE: 0 bf16 A; 1 bf16 A + relu(tscale*a+tshift); 2 fp32 A
// EMODE: 0 o=acc+b; 1 o=acc*rdst+b; 2 o=relu(acc+b)*rsrc; 3 o=relu(acc*rdst+b)*rsrc
template <int AMODE, int EMODE, int OUTBF>
__global__ __launch_bounds__(256) void gemm_mfma(
    const void* __restrict__ Ain, const short* __restrict__ WT,
    const float* __restrict__ bias,
    const float* __restrict__ tscale, const float* __restrict__ tshift,
    const float* __restrict__ rdst, const float* __restrict__ rsrc,
    void* __restrict__ Cout, int M)
{
    __shared__ __align__(16) short sBT[128 * LDSTRIDE];
    const int t = threadIdx.x;
    {   // stage WT (n-major) into padded LDS; 2048 chunks of 8 bf16
        const bh8* g = (const bh8*)WT;
#pragma unroll
        for (int i = 0; i < 8; ++i) {
            int c  = i * 256 + t;
            int n  = c >> 4, c8 = c & 15;
            *(bh8*)&sBT[n * LDSTRIDE + c8 * 8] = g[c];
        }
    }
    __syncthreads();

    const int w    = t >> 6;
    const int lane = t & 63;
    const int ln   = lane & 15;
    const int quad = lane >> 4;
    const int wrow = (w >> 1) * 64;
    const int wcol = (w & 1) * 64;
    const int r0   = blockIdx.x * 128;

    f32x4 acc[4][4] = {};

#pragma unroll
    for (int k0 = 0; k0 < 128; k0 += 32) {
        const int kb = k0 + quad * 8;
        bh8 a[4], b[4];
#pragma unroll
        for (int mt = 0; mt < 4; ++mt) {
            int row = r0 + wrow + mt * 16 + ln;
            row = min(row, M - 1);          // clamp: junk rows never stored
            if (AMODE == 2) {
                const float4* p = (const float4*)((const float*)Ain +
                                                  (size_t)row * D + kb);
                float4 x0 = p[0], x1 = p[1];
                bh8 v;
                v[0] = (short)f2b(x0.x); v[1] = (short)f2b(x0.y);
                v[2] = (short)f2b(x0.z); v[3] = (short)f2b(x0.w);
                v[4] = (short)f2b(x1.x); v[5] = (short)f2b(x1.y);
                v[6] = (short)f2b(x1.z); v[7] = (short)f2b(x1.w);
                a[mt] = v;
            } else {
                bh8 v = *(const bh8*)((const unsigned short*)Ain +
                                      (size_t)row * D + kb);
                if (AMODE == 1) {
                    const float4* sc = (const float4*)(tscale + kb);
                    const float4* sh = (const float4*)(tshift + kb);
                    float4 s0 = sc[0], s1 = sc[1];
                    float4 h0 = sh[0], h1 = sh[1];
                    bh8 o;
                    o[0] = (short)f2b(fmaxf(fmaf(s0.x, b2f((unsigned short)v[0]), h0.x), 0.f));
                    o[1] = (short)f2b(fmaxf(fmaf(s0.y, b2f((unsigned short)v[1]), h0.y), 0.f));
                    o[2] = (short)f2b(fmaxf(fmaf(s0.z, b2f((unsigned short)v[2]), h0.z), 0.f));
                    o[3] = (short)f2b(fmaxf(fmaf(s0.w, b2f((unsigned short)v[3]), h0.w), 0.f));
                    o[4] = (short)f2b(fmaxf(fmaf(s1.x, b2f((unsigned short)v[4]), h1.x), 0.f));
                    o[5] = (short)f2b(fmaxf(fmaf(s1.y, b2f((unsigned short)v[5]), h1.y), 0.f));
                    o[6] = (short)f2b(fmaxf(fmaf(s1.z, b2f((unsigned short)v[6]), h1.z), 0.f));
                    o[7] = (short)f2b(fmaxf(fmaf(s1.w, b2f((unsigned short)v[7]), h1.w), 0.f));
                    v = o;
                }
                a[mt] = v;
            }
        }
#pragma unroll
        for (int nt = 0; nt < 4; ++nt) {
            int n = wcol + nt * 16 + ln;
            b[nt] = *(const bh8*)&sBT[n * LDSTRIDE + kb];
        }
#pragma unroll
        for (int mt = 0; mt < 4; ++mt)
#pragma unroll
            for (int nt = 0; nt < 4; ++nt)
                acc[mt][nt] = __builtin_amdgcn_mfma_f32_16x16x32_bf16(
                    a[mt], b[nt], acc[mt][nt], 0, 0, 0);
    }

    // epilogue: C/D layout col = ln, row = quad*4 + reg
#pragma unroll
    for (int mt = 0; mt < 4; ++mt) {
        const int rb = r0 + wrow + mt * 16 + quad * 4;
        float rd[4], rs[4];
        if (EMODE == 1 || EMODE == 3) {
#pragma unroll
            for (int i = 0; i < 4; ++i) rd[i] = (rb + i < M) ? rdst[rb + i] : 0.f;
        }
        if (EMODE == 2 || EMODE == 3) {
#pragma unroll
            for (int i = 0; i < 4; ++i) rs[i] = (rb + i < M) ? rsrc[rb + i] : 0.f;
        }
#pragma unroll
        for (int nt = 0; nt < 4; ++nt) {
            const int col = wcol + nt * 16 + ln;
            const float bb = bias[col];
#pragma unroll
            for (int i = 0; i < 4; ++i) {
                int row = rb + i;
                if (row < M) {
                    float v = acc[mt][nt][i];
                    float o;
                    if (EMODE == 0)      o = v + bb;
                    else if (EMODE == 1) o = fmaf(v, rd[i], bb);
                    else if (EMODE == 2) o = fmaxf(v + bb, 0.f) * rs[i];
                    else                 o = fmaxf(fmaf(v, rd[i], bb), 0.f) * rs[i];
                    if (OUTBF)
                        ((unsigned short*)Cout)[(size_t)row * D + col] = f2b(o);
                    else
                        ((float*)Cout)[(size_t)row * D + col] = o;
                }
            }
        }
    }
}

// ------------------------------ binned histogram (no global atomics)
// block (c,r): edge chunk c vs node range r; LDS hist; plain stores out.
__global__ __launch_bounds__(256) void edge_hist(
    const int* __restrict__ idx, int* __restrict__ partial,
    int E, int M, int rsize, int csz)
{
    __shared__ int h[12500];   // rsize <= 12500 (50 KB)
    const int t = threadIdx.x;
    const int c = blockIdx.x & (NCH - 1);
    const int r = blockIdx.x >> 5;          // NCH = 32
    for (int k = t; k < rsize; k += 256) h[k] = 0;
    __syncthreads();
    const int lo  = r * rsize;
    const int beg = c * csz;
    const int end = min(E, beg + csz);
    for (int i = beg + t; i < end; i += 256) {
        int s = idx[i] - lo;
        if ((unsigned)s < (unsigned)rsize) atomicAdd(&h[s], 1);
    }
    __syncthreads();
    const int seg = min(rsize, M - lo);
    for (int k = t; k < seg; k += 256)
        partial[(size_t)c * M + lo + k] = h[k];
}

// -------- scan + finish: cursor bases, degrees->norms, BN affine
__global__ __launch_bounds__(256) void scan_fin(
    const int* __restrict__ spartial, const int* __restrict__ dpartial,
    int* __restrict__ cursor_base, int* __restrict__ dstdeg,
    const float* __restrict__ sums, const float* __restrict__ sqs,
    const float* __restrict__ gamma, const float* __restrict__ beta,
    float* __restrict__ scale, float* __restrict__ shift,
    float* __restrict__ nsrc, float* __restrict__ ndst, int M, float invM)
{
    int i = blockIdx.x * 256 + threadIdx.x;
    if (i < M) {
        int sd = 0;
#pragma unroll 8
        for (int c = 0; c < NCH; ++c) sd += spartial[(size_t)c * M + i];
        nsrc[i] = rsqrtf(fmaxf((float)sd, 1.f));
        int run = 0;
#pragma unroll 8
        for (int c = 0; c < NCH; ++c) {
            cursor_base[(size_t)c * M + i] = run;
            run += dpartial[(size_t)c * M + i];
        }
        dstdeg[i] = run;
        ndst[i]   = rsqrtf(fmaxf((float)run, 1.f));
    }
    if (blockIdx.x == 0 && threadIdx.x < D) {
        int c = threadIdx.x;
        float mu  = sums[c] * invM;
        float var = fmaf(-mu, mu, sqs[c] * invM);
        float rs  = rsqrtf(var + 1e-5f);
        float sc  = gamma[c] * rs;
        scale[c]  = sc;
        shift[c]  = fmaf(-mu, sc, beta[c]);
    }
}

// ------------------------- CSR fill: LDS cursors, zero global atomics
__global__ __launch_bounds__(256) void fill_csr(
    const int* __restrict__ src, const int* __restrict__ dst,
    const int* __restrict__ cursor_base, int* __restrict__ csr,
    int E, int M, int rsize, int csz)
{
    __shared__ int cur[12500];
    const int t  = threadIdx.x;
    const int c  = blockIdx.x & (NCH - 1);
    const int r  = blockIdx.x >> 5;
    const int lo = r * rsize;
    const int seg = min(rsize, M - lo);
    for (int k = t; k < seg; k += 256)
        cur[k] = cursor_base[(size_t)c * M + lo + k];
    __syncthreads();
    const int beg = c * csz;
    const int end = min(E, beg + csz);
    for (int i = beg + t; i < end; i += 256) {
        int d = dst[i] - lo;
        int s = src[i];
        if ((unsigned)d < (unsigned)seg) {
            int p = atomicAdd(&cur[d], 1);     // LDS atomic
            if (p < CSR_STRIDE)
                csr[((size_t)(lo + d) << 6) + p] = s;   // plain scattered store
        }
    }
}

// --------------------------------------------- weight transpose+convert
__global__ __launch_bounds__(256) void wprep(
    const float* __restrict__ W1, const float* __restrict__ W2,
    const float* __restrict__ Wc, short* __restrict__ WT)
{
    const float* W = (blockIdx.y == 0) ? W1 : (blockIdx.y == 1) ? W2 : Wc;
    short* T = WT + (size_t)blockIdx.y * D * D;
    int idx = blockIdx.x * 256 + threadIdx.x;
    int k = idx >> 7, n = idx & 127;
    T[n * D + k] = (short)f2b(W[k * D + n]);
}

// ------------------------------------------------------------ BN stats
__global__ __launch_bounds__(256) void bn_stats(
    const unsigned short* __restrict__ H, float* __restrict__ sums,
    float* __restrict__ sqs, int M)
{
    __shared__ float red[256][4];
    const int t  = threadIdx.x;
    const int c2 = t & 63;
    const int rg = t >> 6;
    float s0 = 0.f, q0 = 0.f, s1 = 0.f, q1 = 0.f;
    for (int r = blockIdx.x * 4 + rg; r < M; r += gridDim.x * 4) {
        unsigned u = *(const unsigned*)(H + (size_t)r * D + c2 * 2);
        float x0 = __uint_as_float(u << 16);
        float x1 = __uint_as_float(u & 0xffff0000u);
        s0 += x0; q0 = fmaf(x0, x0, q0);
        s1 += x1; q1 = fmaf(x1, x1, q1);
    }
    red[t][0] = s0; red[t][1] = q0; red[t][2] = s1; red[t][3] = q1;
    __syncthreads();
    if (t < 64) {
        for (int i = 1; i < 4; ++i) {
            red[t][0] += red[t + 64 * i][0];
            red[t][1] += red[t + 64 * i][1];
            red[t][2] += red[t + 64 * i][2];
            red[t][3] += red[t + 64 * i][3];
        }
        unsafeAtomicAdd(&sums[c2 * 2],     red[t][0]);
        unsafeAtomicAdd(&sqs[c2 * 2],      red[t][1]);
        unsafeAtomicAdd(&sums[c2 * 2 + 1], red[t][2]);
        unsafeAtomicAdd(&sqs[c2 * 2 + 1],  red[t][3]);
    }
}

// ------------------------------------------- gather-side aggregation
// 16 threads per dst node; X bf16 already = relu(h)*norm_src; fp32 accum.
// 8 edges in flight per iteration (latency hiding).
__global__ __launch_bounds__(256) void agg_gather(
    const unsigned short* __restrict__ X, const int* __restrict__ deg,
    const int* __restrict__ csr, unsigned short* __restrict__ AGG, int M)
{
    int tid  = blockIdx.x * 256 + threadIdx.x;
    int node = tid >> 4;
    if (node >= M) return;
    int c8  = tid & 15;
    int cnt = min(deg[node], CSR_STRIDE);
    const int* row = csr + ((size_t)node << 6);

    float a0[8] = {0.f, 0.f, 0.f, 0.f, 0.f, 0.f, 0.f, 0.f};
    float a1[8] = {0.f, 0.f, 0.f, 0.f, 0.f, 0.f, 0.f, 0.f};
    int j = 0;
    for (; j + 8 <= cnt; j += 8) {
        int4 s0 = *(const int4*)(row + j);
        int4 s1 = *(const int4*)(row + j + 4);
        bh8 v0 = *(const bh8*)(X + (size_t)s0.x * D + c8 * 8);
        bh8 v1 = *(const bh8*)(X + (size_t)s0.y * D + c8 * 8);
        bh8 v2 = *(const bh8*)(X + (size_t)s0.z * D + c8 * 8);
        bh8 v3 = *(const bh8*)(X + (size_t)s0.w * D + c8 * 8);
        bh8 v4 = *(const bh8*)(X + (size_t)s1.x * D + c8 * 8);
        bh8 v5 = *(const bh8*)(X + (size_t)s1.y * D + c8 * 8);
        bh8 v6 = *(const bh8*)(X + (size_t)s1.z * D + c8 * 8);
        bh8 v7 = *(const bh8*)(X + (size_t)s1.w * D + c8 * 8);
#pragma unroll
        for (int q = 0; q < 8; ++q) {
            a0[q] += b2f((unsigned short)v0[q]) + b2f((unsigned short)v2[q])
                   + b2f((unsigned short)v4[q]) + b2f((unsigned short)v6[q]);
            a1[q] += b2f((unsigned short)v1[q]) + b2f((unsigned short)v3[q])
                   + b2f((unsigned short)v5[q]) + b2f((unsigned short)v7[q]);
        }
    }
    for (; j + 4 <= cnt; j += 4) {
        int4 ss = *(const int4*)(row + j);
        bh8 v0 = *(const bh8*)(X + (size_t)ss.x * D + c8 * 8);
        bh8 v1 = *(const bh8*)(X + (size_t)ss.y * D + c8 * 8);
        bh8 v2 = *(const bh8*)(X + (size_t)ss.z * D + c8 * 8);
        bh8 v3 = *(const bh8*)(X + (size_t)ss.w * D + c8 * 8);
#pragma unroll
        for (int q = 0; q < 8; ++q) {
            a0[q] += b2f((unsigned short)v0[q]) + b2f((unsigned short)v2[q]);
            a1[q] += b2f((unsigned short)v1[q]) + b2f((unsigned short)v3[q]);
        }
    }
    for (; j < cnt; ++j) {
        bh8 v = *(const bh8*)(X + (size_t)row[j] * D + c8 * 8);
#pragma unroll
        for (int q = 0; q < 8; ++q) a0[q] += b2f((unsigned short)v[q]);
    }
    bh8 o;
#pragma unroll
    for (int q = 0; q < 8; ++q) o[q] = (short)f2b(a0[q] + a1[q]);
    *(bh8*)(AGG + (size_t)node * D + c8 * 8) = o;
}

// ---------------------------------------------------------------------
extern "C" void kernel_launch(void* const* d_in, const int* in_sizes, int n_in,
                              void* d_out, int out_size, void* d_ws, size_t ws_size,
                              hipStream_t stream)
{
    const float* in_feat = (const float*)d_in[0];
    const int*   src     = (const int*)d_in[1];
    const int*   dst     = (const int*)d_in[2];
    const float* W1      = (const float*)d_in[3];
    const float* b1      = (const float*)d_in[4];
    const float* gamma   = (const float*)d_in[5];
    const float* beta    = (const float*)d_in[6];
    const float* W2      = (const float*)d_in[7];
    const float* b2      = (const float*)d_in[8];
    const float* Wc      = (const float*)d_in[9];
    const float* bc      = (const float*)d_in[10];
    float*       out     = (float*)d_out;

    const int M = in_sizes[0] / D;   // 100000
    const int E = in_sizes[1];       // 1600000

    const int rsize = (M + NR - 1) / NR;             // 12500 (fits 50 KB LDS)
    const int csz   = (E + NCH - 1) / NCH;           // 50000
    const int GB    = (M + 127) / 128;               // 782

    // workspace layout
    unsigned short* H1b = (unsigned short*)d_ws;        // M*D bf16: h1 / AGG
    unsigned short* Xb  = H1b + (size_t)M * D;          // M*D bf16: X
    int*   spartial = (int*)Xb;                         // NCH*M (aliases Xb lo)
    int*   dpartial = spartial + (size_t)NCH * M;       // NCH*M (aliases Xb hi)
    short* WT      = (short*)(Xb + (size_t)M * D);      // 3*D*D bf16
    int*   dstdeg  = (int*)(WT + 3 * D * D);            // M
    float* sums    = (float*)(dstdeg + M);              // 128
    float* sqs     = sums + D;                          // 128
    float* scale   = sqs + D;                           // 128
    float* shift   = scale + D;                         // 128
    float* nsrc    = shift + D;                         // M
    float* ndst    = nsrc + M;                          // M
    int*   csr     = (int*)(ndst + M);                  // M * CSR_STRIDE
    int*   cursor_base = csr + (size_t)M * CSR_STRIDE;  // NCH*M

    // zero sums + sqs only (degrees are plain-stored now)
    hipMemsetAsync(sums, 0, 2 * D * sizeof(float), stream);

    wprep<<<dim3(64, 3), 256, 0, stream>>>(W1, W2, Wc, WT);

    // binned histograms (no global atomics)
    edge_hist<<<NCH * NR, 256, 0, stream>>>(src, spartial, E, M, rsize, csz);
    edge_hist<<<NCH * NR, 256, 0, stream>>>(dst, dpartial, E, M, rsize, csz);

    // gemm1: H1b = bf16(in_feat @ W1 + b1)
    gemm_mfma<2, 0, 1><<<GB, 256, 0, stream>>>(in_feat, WT, b1, nullptr,
                                               nullptr, nullptr, nullptr,
                                               H1b, M);
    bn_stats<<<256, 256, 0, stream>>>(H1b, sums, sqs, M);

    // scan: cursor bases + degrees -> norms + BN affine
    scan_fin<<<(M + 255) / 256, 256, 0, stream>>>(spartial, dpartial,
                                                  cursor_base, dstdeg, sums,
                                                  sqs, gamma, beta, scale,
                                                  shift, nsrc, ndst, M,
                                                  1.f / (float)M);

    // CSR fill: LDS cursors, plain stores
    fill_csr<<<NCH * NR, 256, 0, stream>>>(src, dst, cursor_base, csr,
                                           E, M, rsize, csz);

    // gemm2: Xb = bf16( relu( BNReLU(H1b) @ W2 + b2 ) * nsrc )  (kills partials)
    gemm_mfma<1, 2, 1><<<GB, 256, 0, stream>>>(H1b, WT + D * D, b2, scale,
                                               shift, nullptr, nsrc, Xb, M);

    const int ab = (int)(((long long)M * 16 + 255) / 256);
    for (int step = 0; step < 3; ++step) {
        agg_gather<<<ab, 256, 0, stream>>>(Xb, dstdeg, csr, H1b, M);
        if (step < 2) {
            gemm_mfma<0, 3, 1><<<GB, 256, 0, stream>>>(H1b, WT + 2 * D * D, bc,
                                                       nullptr, nullptr, ndst,
                                                       nsrc, Xb, M);
        } else {
            gemm_mfma<0, 1, 0><<<GB, 256, 0, stream>>>(H1b, WT + 2 * D * D, bc,
                                                       nullptr, nullptr, ndst,
                                                       nsrc, out, M);
        }
    }
}

// Round 8
// 553.602 us; speedup vs baseline: 1.3737x; 1.3737x over previous
//
#include <hip/hip_runtime.h>

#define D 128
#define CSR_STRIDE 64     // in-deg ~ Poisson(16); P(>64) ~ 0, guarded anyway
#define LDSTRIDE 136      // 128 + 8 pad: 16B-aligned, 2-way banks (free)
#define NCH 64            // edge chunks for binned histogram / fill
#define NR  16            // node ranges (6250 nodes * 4B = 25 KB LDS)

typedef short bh8 __attribute__((ext_vector_type(8)));
typedef float f32x4 __attribute__((ext_vector_type(4)));

__device__ __forceinline__ unsigned short f2b(float f) {
    unsigned u = __float_as_uint(f);
    u += 0x7fffu + ((u >> 16) & 1u);          // RNE
    return (unsigned short)(u >> 16);
}
__device__ __forceinline__ float b2f(unsigned short h) {
    return __uint_as_float(((unsigned)h) << 16);
}

// ------------------------------------------------------------ MFMA GEMM
// C[M x 128] = A[M x 128] @ W[128 x 128] via 16x16x32 bf16 MFMA.
// 256 thr = 4 waves; tile 128x128; wave = 64x64 (4x4 mfma). WT is n-major.
// AMODE: 0 bf16 A; 1 bf16 A + relu(tscale*a+tshift); 2 fp32 A
// EMODE: 0 o=acc+b; 1 o=acc*rdst+b; 2 o=relu(acc+b)*rsrc; 3 o=relu(acc*rdst+b)*rsrc
template <int AMODE, int EMODE, int OUTBF>
__global__ __launch_bounds__(256) void gemm_mfma(
    const void* __restrict__ Ain, const short* __restrict__ WT,
    const float* __restrict__ bias,
    const float* __restrict__ tscale, const float* __restrict__ tshift,
    const float* __restrict__ rdst, const float* __restrict__ rsrc,
    void* __restrict__ Cout, int M)
{
    __shared__ __align__(16) short sBT[128 * LDSTRIDE];
    const int t = threadIdx.x;
    {   // stage WT (n-major) into padded LDS; 2048 chunks of 8 bf16
        const bh8* g = (const bh8*)WT;
#pragma unroll
        for (int i = 0; i < 8; ++i) {
            int c  = i * 256 + t;
            int n  = c >> 4, c8 = c & 15;
            *(bh8*)&sBT[n * LDSTRIDE + c8 * 8] = g[c];
        }
    }
    __syncthreads();

    const int w    = t >> 6;
    const int lane = t & 63;
    const int ln   = lane & 15;
    const int quad = lane >> 4;
    const int wrow = (w >> 1) * 64;
    const int wcol = (w & 1) * 64;
    const int r0   = blockIdx.x * 128;

    f32x4 acc[4][4] = {};

#pragma unroll
    for (int k0 = 0; k0 < 128; k0 += 32) {
        const int kb = k0 + quad * 8;
        bh8 a[4], b[4];
#pragma unroll
        for (int mt = 0; mt < 4; ++mt) {
            int row = r0 + wrow + mt * 16 + ln;
            row = min(row, M - 1);          // clamp: junk rows never stored
            if (AMODE == 2) {
                const float4* p = (const float4*)((const float*)Ain +
                                                  (size_t)row * D + kb);
                float4 x0 = p[0], x1 = p[1];
                bh8 v;
                v[0] = (short)f2b(x0.x); v[1] = (short)f2b(x0.y);
                v[2] = (short)f2b(x0.z); v[3] = (short)f2b(x0.w);
                v[4] = (short)f2b(x1.x); v[5] = (short)f2b(x1.y);
                v[6] = (short)f2b(x1.z); v[7] = (short)f2b(x1.w);
                a[mt] = v;
            } else {
                bh8 v = *(const bh8*)((const unsigned short*)Ain +
                                      (size_t)row * D + kb);
                if (AMODE == 1) {
                    const float4* sc = (const float4*)(tscale + kb);
                    const float4* sh = (const float4*)(tshift + kb);
                    float4 s0 = sc[0], s1 = sc[1];
                    float4 h0 = sh[0], h1 = sh[1];
                    bh8 o;
                    o[0] = (short)f2b(fmaxf(fmaf(s0.x, b2f((unsigned short)v[0]), h0.x), 0.f));
                    o[1] = (short)f2b(fmaxf(fmaf(s0.y, b2f((unsigned short)v[1]), h0.y), 0.f));
                    o[2] = (short)f2b(fmaxf(fmaf(s0.z, b2f((unsigned short)v[2]), h0.z), 0.f));
                    o[3] = (short)f2b(fmaxf(fmaf(s0.w, b2f((unsigned short)v[3]), h0.w), 0.f));
                    o[4] = (short)f2b(fmaxf(fmaf(s1.x, b2f((unsigned short)v[4]), h1.x), 0.f));
                    o[5] = (short)f2b(fmaxf(fmaf(s1.y, b2f((unsigned short)v[5]), h1.y), 0.f));
                    o[6] = (short)f2b(fmaxf(fmaf(s1.z, b2f((unsigned short)v[6]), h1.z), 0.f));
                    o[7] = (short)f2b(fmaxf(fmaf(s1.w, b2f((unsigned short)v[7]), h1.w), 0.f));
                    v = o;
                }
                a[mt] = v;
            }
        }
#pragma unroll
        for (int nt = 0; nt < 4; ++nt) {
            int n = wcol + nt * 16 + ln;
            b[nt] = *(const bh8*)&sBT[n * LDSTRIDE + kb];
        }
#pragma unroll
        for (int mt = 0; mt < 4; ++mt)
#pragma unroll
            for (int nt = 0; nt < 4; ++nt)
                acc[mt][nt] = __builtin_amdgcn_mfma_f32_16x16x32_bf16(
                    a[mt], b[nt], acc[mt][nt], 0, 0, 0);
    }

    // epilogue: C/D layout col = ln, row = quad*4 + reg
#pragma unroll
    for (int mt = 0; mt < 4; ++mt) {
        const int rb = r0 + wrow + mt * 16 + quad * 4;
        float rd[4], rs[4];
        if (EMODE == 1 || EMODE == 3) {
#pragma unroll
            for (int i = 0; i < 4; ++i) rd[i] = (rb + i < M) ? rdst[rb + i] : 0.f;
        }
        if (EMODE == 2 || EMODE == 3) {
#pragma unroll
            for (int i = 0; i < 4; ++i) rs[i] = (rb + i < M) ? rsrc[rb + i] : 0.f;
        }
#pragma unroll
        for (int nt = 0; nt < 4; ++nt) {
            const int col = wcol + nt * 16 + ln;
            const float bb = bias[col];
#pragma unroll
            for (int i = 0; i < 4; ++i) {
                int row = rb + i;
                if (row < M) {
                    float v = acc[mt][nt][i];
                    float o;
                    if (EMODE == 0)      o = v + bb;
                    else if (EMODE == 1) o = fmaf(v, rd[i], bb);
                    else if (EMODE == 2) o = fmaxf(v + bb, 0.f) * rs[i];
                    else                 o = fmaxf(fmaf(v, rd[i], bb), 0.f) * rs[i];
                    if (OUTBF)
                        ((unsigned short*)Cout)[(size_t)row * D + col] = f2b(o);
                    else
                        ((float*)Cout)[(size_t)row * D + col] = o;
                }
            }
        }
    }
}

// ------------------------------ binned histograms (no global atomics)
// grid (NCH*NR, 2): blockIdx.y picks src/dst. block (c,r): edge chunk c
// vs node range r; 25 KB LDS hist; uint8 partial counts out (deg < 256).
__global__ __launch_bounds__(256) void edge_hist2(
    const int* __restrict__ src, const int* __restrict__ dst,
    unsigned char* __restrict__ spartial, unsigned char* __restrict__ dpartial,
    int E, int M, int rsize, int csz)
{
    __shared__ int h[6250];   // rsize <= 6250
    const int t = threadIdx.x;
    const int c = blockIdx.x & (NCH - 1);
    const int r = blockIdx.x >> 6;          // NCH = 64
    const int* __restrict__ idx = blockIdx.y ? dst : src;
    unsigned char* __restrict__ part = blockIdx.y ? dpartial : spartial;
    for (int k = t; k < rsize; k += 256) h[k] = 0;
    __syncthreads();
    const int lo  = r * rsize;
    const int beg = c * csz;
    const int end = min(E, beg + csz);
    const int4* p4 = (const int4*)idx;
    for (int i = (beg >> 2) + t; i < (end >> 2); i += 256) {
        int4 v = p4[i];
        int a0 = v.x - lo, a1 = v.y - lo, a2 = v.z - lo, a3 = v.w - lo;
        if ((unsigned)a0 < (unsigned)rsize) atomicAdd(&h[a0], 1);
        if ((unsigned)a1 < (unsigned)rsize) atomicAdd(&h[a1], 1);
        if ((unsigned)a2 < (unsigned)rsize) atomicAdd(&h[a2], 1);
        if ((unsigned)a3 < (unsigned)rsize) atomicAdd(&h[a3], 1);
    }
    for (int i = (end & ~3) + t; i < end; i += 256) {      // tail
        int a = idx[i] - lo;
        if ((unsigned)a < (unsigned)rsize) atomicAdd(&h[a], 1);
    }
    __syncthreads();
    const int seg = min(rsize, M - lo);
    for (int k = t; k < seg; k += 256)
        part[(size_t)c * M + lo + k] = (unsigned char)h[k];
}

// -------- scan: per-node chunk prefix (uint8 cursor bases) + degrees/norms
__global__ __launch_bounds__(256) void scan_fin(
    const unsigned char* __restrict__ spartial,
    const unsigned char* __restrict__ dpartial,
    unsigned char* __restrict__ cursor_base, int* __restrict__ dstdeg,
    float* __restrict__ nsrc, float* __restrict__ ndst, int M)
{
    int i = blockIdx.x * 256 + threadIdx.x;
    if (i >= M) return;
    int sd = 0;
#pragma unroll 8
    for (int c = 0; c < NCH; ++c) sd += spartial[(size_t)c * M + i];
    nsrc[i] = rsqrtf(fmaxf((float)sd, 1.f));
    int run = 0;
#pragma unroll 8
    for (int c = 0; c < NCH; ++c) {
        cursor_base[(size_t)c * M + i] = (unsigned char)run;
        run += dpartial[(size_t)c * M + i];
    }
    dstdeg[i] = run;
    ndst[i]   = rsqrtf(fmaxf((float)run, 1.f));
}

// ------------------------- CSR fill: LDS cursors, zero global atomics
__global__ __launch_bounds__(256) void fill_csr(
    const int* __restrict__ src, const int* __restrict__ dst,
    const unsigned char* __restrict__ cursor_base, int* __restrict__ csr,
    int E, int M, int rsize, int csz)
{
    __shared__ int cur[6250];
    const int t  = threadIdx.x;
    const int c  = blockIdx.x & (NCH - 1);
    const int r  = blockIdx.x >> 6;
    const int lo = r * rsize;
    const int seg = min(rsize, M - lo);
    for (int k = t; k < seg; k += 256)
        cur[k] = cursor_base[(size_t)c * M + lo + k];
    __syncthreads();
    const int beg = c * csz;
    const int end = min(E, beg + csz);
    const int4* s4 = (const int4*)src;
    const int4* d4 = (const int4*)dst;
    for (int i = (beg >> 2) + t; i < (end >> 2); i += 256) {
        int4 dv = d4[i];
        int4 sv = s4[i];
        int a0 = dv.x - lo, a1 = dv.y - lo, a2 = dv.z - lo, a3 = dv.w - lo;
        if ((unsigned)a0 < (unsigned)seg) {
            int p = atomicAdd(&cur[a0], 1);
            if (p < CSR_STRIDE) csr[((size_t)(lo + a0) << 6) + p] = sv.x;
        }
        if ((unsigned)a1 < (unsigned)seg) {
            int p = atomicAdd(&cur[a1], 1);
            if (p < CSR_STRIDE) csr[((size_t)(lo + a1) << 6) + p] = sv.y;
        }
        if ((unsigned)a2 < (unsigned)seg) {
            int p = atomicAdd(&cur[a2], 1);
            if (p < CSR_STRIDE) csr[((size_t)(lo + a2) << 6) + p] = sv.z;
        }
        if ((unsigned)a3 < (unsigned)seg) {
            int p = atomicAdd(&cur[a3], 1);
            if (p < CSR_STRIDE) csr[((size_t)(lo + a3) << 6) + p] = sv.w;
        }
    }
    for (int i = (end & ~3) + t; i < end; i += 256) {      // tail
        int d = dst[i] - lo;
        if ((unsigned)d < (unsigned)seg) {
            int p = atomicAdd(&cur[d], 1);
            if (p < CSR_STRIDE) csr[((size_t)(lo + d) << 6) + p] = src[i];
        }
    }
}

// --------------------------------------------- weight transpose+convert
__global__ __launch_bounds__(256) void wprep(
    const float* __restrict__ W1, const float* __restrict__ W2,
    const float* __restrict__ Wc, short* __restrict__ WT)
{
    const float* W = (blockIdx.y == 0) ? W1 : (blockIdx.y == 1) ? W2 : Wc;
    short* T = WT + (size_t)blockIdx.y * D * D;
    int idx = blockIdx.x * 256 + threadIdx.x;
    int k = idx >> 7, n = idx & 127;
    T[n * D + k] = (short)f2b(W[k * D + n]);
}

// ------------------------------------------------------------ BN stats
__global__ __launch_bounds__(256) void bn_stats(
    const unsigned short* __restrict__ H, float* __restrict__ sums,
    float* __restrict__ sqs, int M)
{
    __shared__ float red[256][4];
    const int t  = threadIdx.x;
    const int c2 = t & 63;
    const int rg = t >> 6;
    float s0 = 0.f, q0 = 0.f, s1 = 0.f, q1 = 0.f;
    for (int r = blockIdx.x * 4 + rg; r < M; r += gridDim.x * 4) {
        unsigned u = *(const unsigned*)(H + (size_t)r * D + c2 * 2);
        float x0 = __uint_as_float(u << 16);
        float x1 = __uint_as_float(u & 0xffff0000u);
        s0 += x0; q0 = fmaf(x0, x0, q0);
        s1 += x1; q1 = fmaf(x1, x1, q1);
    }
    red[t][0] = s0; red[t][1] = q0; red[t][2] = s1; red[t][3] = q1;
    __syncthreads();
    if (t < 64) {
        for (int i = 1; i < 4; ++i) {
            red[t][0] += red[t + 64 * i][0];
            red[t][1] += red[t + 64 * i][1];
            red[t][2] += red[t + 64 * i][2];
            red[t][3] += red[t + 64 * i][3];
        }
        unsafeAtomicAdd(&sums[c2 * 2],     red[t][0]);
        unsafeAtomicAdd(&sqs[c2 * 2],      red[t][1]);
        unsafeAtomicAdd(&sums[c2 * 2 + 1], red[t][2]);
        unsafeAtomicAdd(&sqs[c2 * 2 + 1],  red[t][3]);
    }
}

__global__ void bn_final(const float* __restrict__ sums,
                         const float* __restrict__ sqs,
                         const float* __restrict__ gamma,
                         const float* __restrict__ beta,
                         float* __restrict__ scale,
                         float* __restrict__ shift, float invM)
{
    int c = threadIdx.x;
    float mu  = sums[c] * invM;
    float var = fmaf(-mu, mu, sqs[c] * invM);
    float rs  = rsqrtf(var + 1e-5f);
    float sc  = gamma[c] * rs;
    scale[c]  = sc;
    shift[c]  = fmaf(-mu, sc, beta[c]);
}

// ------------------------------------------- gather-side aggregation
// 16 threads per dst node; X bf16 already = relu(h)*norm_src; fp32 accum.
__global__ __launch_bounds__(256) void agg_gather(
    const unsigned short* __restrict__ X, const int* __restrict__ deg,
    const int* __restrict__ csr, unsigned short* __restrict__ AGG, int M)
{
    int tid  = blockIdx.x * 256 + threadIdx.x;
    int node = tid >> 4;
    if (node >= M) return;
    int c8  = tid & 15;
    int cnt = min(deg[node], CSR_STRIDE);
    const int* row = csr + ((size_t)node << 6);

    float a0[8] = {0.f, 0.f, 0.f, 0.f, 0.f, 0.f, 0.f, 0.f};
    float a1[8] = {0.f, 0.f, 0.f, 0.f, 0.f, 0.f, 0.f, 0.f};
    int j = 0;
    for (; j + 8 <= cnt; j += 8) {
        int4 s0 = *(const int4*)(row + j);
        int4 s1 = *(const int4*)(row + j + 4);
        bh8 v0 = *(const bh8*)(X + (size_t)s0.x * D + c8 * 8);
        bh8 v1 = *(const bh8*)(X + (size_t)s0.y * D + c8 * 8);
        bh8 v2 = *(const bh8*)(X + (size_t)s0.z * D + c8 * 8);
        bh8 v3 = *(const bh8*)(X + (size_t)s0.w * D + c8 * 8);
        bh8 v4 = *(const bh8*)(X + (size_t)s1.x * D + c8 * 8);
        bh8 v5 = *(const bh8*)(X + (size_t)s1.y * D + c8 * 8);
        bh8 v6 = *(const bh8*)(X + (size_t)s1.z * D + c8 * 8);
        bh8 v7 = *(const bh8*)(X + (size_t)s1.w * D + c8 * 8);
#pragma unroll
        for (int q = 0; q < 8; ++q) {
            a0[q] += b2f((unsigned short)v0[q]) + b2f((unsigned short)v2[q])
                   + b2f((unsigned short)v4[q]) + b2f((unsigned short)v6[q]);
            a1[q] += b2f((unsigned short)v1[q]) + b2f((unsigned short)v3[q])
                   + b2f((unsigned short)v5[q]) + b2f((unsigned short)v7[q]);
        }
    }
    for (; j + 4 <= cnt; j += 4) {
        int4 ss = *(const int4*)(row + j);
        bh8 v0 = *(const bh8*)(X + (size_t)ss.x * D + c8 * 8);
        bh8 v1 = *(const bh8*)(X + (size_t)ss.y * D + c8 * 8);
        bh8 v2 = *(const bh8*)(X + (size_t)ss.z * D + c8 * 8);
        bh8 v3 = *(const bh8*)(X + (size_t)ss.w * D + c8 * 8);
#pragma unroll
        for (int q = 0; q < 8; ++q) {
            a0[q] += b2f((unsigned short)v0[q]) + b2f((unsigned short)v2[q]);
            a1[q] += b2f((unsigned short)v1[q]) + b2f((unsigned short)v3[q]);
        }
    }
    for (; j < cnt; ++j) {
        bh8 v = *(const bh8*)(X + (size_t)row[j] * D + c8 * 8);
#pragma unroll
        for (int q = 0; q < 8; ++q) a0[q] += b2f((unsigned short)v[q]);
    }
    bh8 o;
#pragma unroll
    for (int q = 0; q < 8; ++q) o[q] = (short)f2b(a0[q] + a1[q]);
    *(bh8*)(AGG + (size_t)node * D + c8 * 8) = o;
}

// ---------------------------------------------------------------------
extern "C" void kernel_launch(void* const* d_in, const int* in_sizes, int n_in,
                              void* d_out, int out_size, void* d_ws, size_t ws_size,
                              hipStream_t stream)
{
    const float* in_feat = (const float*)d_in[0];
    const int*   src     = (const int*)d_in[1];
    const int*   dst     = (const int*)d_in[2];
    const float* W1      = (const float*)d_in[3];
    const float* b1      = (const float*)d_in[4];
    const float* gamma   = (const float*)d_in[5];
    const float* beta    = (const float*)d_in[6];
    const float* W2      = (const float*)d_in[7];
    const float* b2      = (const float*)d_in[8];
    const float* Wc      = (const float*)d_in[9];
    const float* bc      = (const float*)d_in[10];
    float*       out     = (float*)d_out;

    const int M = in_sizes[0] / D;   // 100000
    const int E = in_sizes[1];       // 1600000

    const int rsize = (M + NR - 1) / NR;             // 6250 (25 KB LDS)
    const int csz   = (E + NCH - 1) / NCH;           // 25000
    const int GB    = (M + 127) / 128;               // 782

    // workspace layout
    unsigned short* H1b = (unsigned short*)d_ws;        // M*D bf16: h1 / AGG
    unsigned short* Xb  = H1b + (size_t)M * D;          // M*D bf16: X
    // partial tables (uint8, 2*NCH*M = 12.8 MB) alias H1b (dead until gemm1)
    unsigned char* spartial = (unsigned char*)H1b;
    unsigned char* dpartial = spartial + (size_t)NCH * M;
    short* WT      = (short*)(Xb + (size_t)M * D);      // 3*D*D bf16
    int*   dstdeg  = (int*)(WT + 3 * D * D);            // M
    float* sums    = (float*)(dstdeg + M);              // 128
    float* sqs     = sums + D;                          // 128
    float* scale   = sqs + D;                           // 128
    float* shift   = scale + D;                         // 128
    float* nsrc    = shift + D;                         // M
    float* ndst    = nsrc + M;                          // M
    int*   csr     = (int*)(ndst + M);                  // M * CSR_STRIDE
    unsigned char* cursor_base = (unsigned char*)(csr + (size_t)M * CSR_STRIDE); // NCH*M

    // zero sums + sqs only
    hipMemsetAsync(sums, 0, 2 * D * sizeof(float), stream);

    wprep<<<dim3(64, 3), 256, 0, stream>>>(W1, W2, Wc, WT);

    // graph pipeline (all before the MLP so partials can alias H1b)
    edge_hist2<<<dim3(NCH * NR, 2), 256, 0, stream>>>(src, dst, spartial,
                                                      dpartial, E, M, rsize, csz);
    scan_fin<<<(M + 255) / 256, 256, 0, stream>>>(spartial, dpartial,
                                                  cursor_base, dstdeg,
                                                  nsrc, ndst, M);
    fill_csr<<<NCH * NR, 256, 0, stream>>>(src, dst, cursor_base, csr,
                                           E, M, rsize, csz);

    // MLP
    gemm_mfma<2, 0, 1><<<GB, 256, 0, stream>>>(in_feat, WT, b1, nullptr,
                                               nullptr, nullptr, nullptr,
                                               H1b, M);
    bn_stats<<<256, 256, 0, stream>>>(H1b, sums, sqs, M);
    bn_final<<<1, 128, 0, stream>>>(sums, sqs, gamma, beta, scale, shift,
                                    1.f / (float)M);
    gemm_mfma<1, 2, 1><<<GB, 256, 0, stream>>>(H1b, WT + D * D, b2, scale,
                                               shift, nullptr, nsrc, Xb, M);

    const int ab = (int)(((long long)M * 16 + 255) / 256);
    for (int step = 0; step < 3; ++step) {
        agg_gather<<<ab, 256, 0, stream>>>(Xb, dstdeg, csr, H1b, M);
        if (step < 2) {
            gemm_mfma<0, 3, 1><<<GB, 256, 0, stream>>>(H1b, WT + 2 * D * D, bc,
                                                       nullptr, nullptr, ndst,
                                                       nsrc, Xb, M);
        } else {
            gemm_mfma<0, 1, 0><<<GB, 256, 0, stream>>>(H1b, WT + 2 * D * D, bc,
                                                       nullptr, nullptr, ndst,
                                                       nsrc, out, M);
        }
    }
}